// Round 1
// baseline (3186.969 us; speedup 1.0000x reference)
//
#include <hip/hip_runtime.h>

#define USER_NUM 80000
#define ITEM_NUM 40000
#define NNODE (USER_NUM + ITEM_NUM)
#define EMB 64

// ---------------------------------------------------------------------------
// init: x = concat(user_emb, item_emb); out = 0   (d_out/d_ws are poisoned
// with 0xAA before every call, so we must re-init every launch)
// ---------------------------------------------------------------------------
__global__ void init_kernel(const float* __restrict__ user_emb,
                            const float* __restrict__ item_emb,
                            float* __restrict__ x,
                            float* __restrict__ out) {
    int idx = blockIdx.x * blockDim.x + threadIdx.x;       // float4 granularity
    const int total = NNODE * EMB / 4;
    if (idx >= total) return;
    const int user_total = USER_NUM * EMB / 4;
    float4 v = (idx < user_total)
                   ? ((const float4*)user_emb)[idx]
                   : ((const float4*)item_emb)[idx - user_total];
    ((float4*)x)[idx]   = v;
    ((float4*)out)[idx] = make_float4(0.f, 0.f, 0.f, 0.f);
}

// ---------------------------------------------------------------------------
// scatter: y[rows[e]] += vals[e] * x[cols[e]]   (COO SpMM, 16 threads/edge,
// float4 per thread -> 4 fp32 atomics, contiguous across the 16 threads)
// ---------------------------------------------------------------------------
__global__ void scatter_kernel(const float* __restrict__ x,
                               float* __restrict__ y,
                               const float* __restrict__ vals,
                               const int* __restrict__ rows,
                               const int* __restrict__ cols,
                               int nnz) {
    int tid = blockIdx.x * blockDim.x + threadIdx.x;
    int e = tid >> 4;
    if (e >= nnz) return;
    int c = tid & 15;

    int   r   = rows[e];
    int   col = cols[e];
    float v   = vals[e];

    float4 xv = ((const float4*)(x + (size_t)col * EMB))[c];
    float* dst = y + (size_t)r * EMB + (size_t)c * 4;
    atomicAdd(dst + 0, xv.x * v);
    atomicAdd(dst + 1, xv.y * v);
    atomicAdd(dst + 2, xv.z * v);
    atomicAdd(dst + 3, xv.w * v);
}

// ---------------------------------------------------------------------------
// accumulate: out += y   (and on the final layer, fused *= 1/3)
// ---------------------------------------------------------------------------
__global__ void accum_kernel(float* __restrict__ out, const float* __restrict__ y) {
    int idx = blockIdx.x * blockDim.x + threadIdx.x;
    const int total = NNODE * EMB / 4;
    if (idx >= total) return;
    float4 o = ((float4*)out)[idx];
    float4 a = ((const float4*)y)[idx];
    o.x += a.x; o.y += a.y; o.z += a.z; o.w += a.w;
    ((float4*)out)[idx] = o;
}

__global__ void accum_scale_kernel(float* __restrict__ out, const float* __restrict__ y) {
    int idx = blockIdx.x * blockDim.x + threadIdx.x;
    const int total = NNODE * EMB / 4;
    if (idx >= total) return;
    const float s = 1.0f / 3.0f;
    float4 o = ((float4*)out)[idx];
    float4 a = ((const float4*)y)[idx];
    o.x = (o.x + a.x) * s; o.y = (o.y + a.y) * s;
    o.z = (o.z + a.z) * s; o.w = (o.w + a.w) * s;
    ((float4*)out)[idx] = o;
}

extern "C" void kernel_launch(void* const* d_in, const int* in_sizes, int n_in,
                              void* d_out, int out_size, void* d_ws, size_t ws_size,
                              hipStream_t stream) {
    const float* user_emb = (const float*)d_in[0];
    const float* item_emb = (const float*)d_in[1];
    const float* vals     = (const float*)d_in[2];
    const int*   rows     = (const int*)d_in[3];
    const int*   cols     = (const int*)d_in[4];
    const int    nnz      = in_sizes[2];

    float* out = (float*)d_out;
    float* x   = (float*)d_ws;                       // 120000*64*4 = 30.72 MB
    float* y   = x + (size_t)NNODE * EMB;            // another 30.72 MB

    const size_t emb_bytes = (size_t)NNODE * EMB * sizeof(float);

    // init x and zero out
    {
        int total = NNODE * EMB / 4;
        int blocks = (total + 255) / 256;
        init_kernel<<<blocks, 256, 0, stream>>>(user_emb, item_emb, x, out);
    }

    for (int layer = 0; layer < 3; ++layer) {
        hipMemsetAsync(y, 0, emb_bytes, stream);
        {
            long long threads = (long long)nnz * 16;
            int blocks = (int)((threads + 255) / 256);
            scatter_kernel<<<blocks, 256, 0, stream>>>(x, y, vals, rows, cols, nnz);
        }
        {
            int total = NNODE * EMB / 4;
            int blocks = (total + 255) / 256;
            if (layer < 2)
                accum_kernel<<<blocks, 256, 0, stream>>>(out, y);
            else
                accum_scale_kernel<<<blocks, 256, 0, stream>>>(out, y);
        }
        // swap x <-> y
        float* t = x; x = y; y = t;
    }
}

// Round 2
// 578.427 us; speedup vs baseline: 5.5097x; 5.5097x over previous
//
#include <hip/hip_runtime.h>

#define USER_NUM 80000
#define ITEM_NUM 40000
#define NNODE (USER_NUM + ITEM_NUM)
#define EMB 64
#define SCAN_BS 256

// ===========================================================================
// CSR build
// ===========================================================================
__global__ void hist_kernel(const int* __restrict__ rows, int* __restrict__ counts, int nnz) {
    int i = blockIdx.x * blockDim.x + threadIdx.x;
    if (i < nnz) atomicAdd(&counts[rows[i]], 1);
}

__global__ void block_sum_kernel(const int* __restrict__ counts, int* __restrict__ bsums, int n) {
    __shared__ int lds[SCAN_BS];
    int t = threadIdx.x;
    int i = blockIdx.x * SCAN_BS + t;
    lds[t] = (i < n) ? counts[i] : 0;
    __syncthreads();
    for (int off = SCAN_BS / 2; off > 0; off >>= 1) {
        if (t < off) lds[t] += lds[t + off];
        __syncthreads();
    }
    if (t == 0) bsums[blockIdx.x] = lds[0];
}

// single block of 512 threads, exclusive scan of nb (<=512) block sums in place
__global__ void scan_bsums_kernel(int* bsums, int nb) {
    __shared__ int lds[512];
    int t = threadIdx.x;
    int v = (t < nb) ? bsums[t] : 0;
    lds[t] = v;
    __syncthreads();
    for (int off = 1; off < 512; off <<= 1) {
        int add = (t >= off) ? lds[t - off] : 0;
        __syncthreads();
        lds[t] += add;
        __syncthreads();
    }
    if (t < nb) bsums[t] = lds[t] - v;  // exclusive
}

__global__ void write_rowptr_kernel(const int* __restrict__ counts, const int* __restrict__ bsums,
                                    int* __restrict__ row_ptr, int* __restrict__ cursor,
                                    int n, int nnz) {
    __shared__ int lds[SCAN_BS];
    int t = threadIdx.x;
    int i = blockIdx.x * SCAN_BS + t;
    int v = (i < n) ? counts[i] : 0;
    lds[t] = v;
    __syncthreads();
    for (int off = 1; off < SCAN_BS; off <<= 1) {
        int add = (t >= off) ? lds[t - off] : 0;
        __syncthreads();
        lds[t] += add;
        __syncthreads();
    }
    if (i < n) {
        int ex = lds[t] - v + bsums[blockIdx.x];
        row_ptr[i] = ex;
        cursor[i]  = ex;
    }
    if (i == 0) row_ptr[n] = nnz;
}

__global__ void fill_kernel(const int* __restrict__ rows, const int* __restrict__ cols,
                            const float* __restrict__ vals, int* __restrict__ cursor,
                            int* __restrict__ cols_s, float* __restrict__ vals_s, int nnz) {
    int i = blockIdx.x * blockDim.x + threadIdx.x;
    if (i >= nnz) return;
    int r = rows[i];
    int pos = atomicAdd(&cursor[r], 1);
    cols_s[pos] = cols[i];
    vals_s[pos] = vals[i];
}

// ===========================================================================
// CSR SpMM: one wave per row, lane = emb dim. Epilogue fuses the layer
// accumulation: L1: out=y1; L2: out+=y2; L3: out=(out+y3)/3.
// ===========================================================================
template <int LAYER>
__global__ void spmm_kernel(const float* __restrict__ xsrc_u, const float* __restrict__ xsrc_i,
                            const int* __restrict__ row_ptr,
                            const int* __restrict__ cols_s, const float* __restrict__ vals_s,
                            float* __restrict__ y, float* __restrict__ out) {
    int wave = (blockIdx.x * blockDim.x + threadIdx.x) >> 6;
    int lane = threadIdx.x & 63;
    if (wave >= NNODE) return;
    int start = row_ptr[wave];
    int end   = row_ptr[wave + 1];
    float acc = 0.f;
    for (int j = start; j < end; ++j) {
        int   c = cols_s[j];
        float v = vals_s[j];
        const float* src;
        if (LAYER == 1)
            src = (c < USER_NUM) ? xsrc_u + (size_t)c * EMB
                                 : xsrc_i + (size_t)(c - USER_NUM) * EMB;
        else
            src = xsrc_u + (size_t)c * EMB;
        acc += v * src[lane];
    }
    size_t o = (size_t)wave * EMB + lane;
    if (LAYER == 1) {
        y[o] = acc;
        out[o] = acc;
    } else if (LAYER == 2) {
        y[o] = acc;
        out[o] += acc;
    } else {
        out[o] = (out[o] + acc) * (1.0f / 3.0f);
    }
}

// ===========================================================================
// Fallback (round-1 atomic path) in case ws_size is too small for CSR arrays
// ===========================================================================
__global__ void init_kernel(const float* __restrict__ user_emb, const float* __restrict__ item_emb,
                            float* __restrict__ x, float* __restrict__ out) {
    int idx = blockIdx.x * blockDim.x + threadIdx.x;
    const int total = NNODE * EMB / 4;
    if (idx >= total) return;
    const int user_total = USER_NUM * EMB / 4;
    float4 v = (idx < user_total) ? ((const float4*)user_emb)[idx]
                                  : ((const float4*)item_emb)[idx - user_total];
    ((float4*)x)[idx]   = v;
    ((float4*)out)[idx] = make_float4(0.f, 0.f, 0.f, 0.f);
}

__global__ void scatter_kernel(const float* __restrict__ x, float* __restrict__ y,
                               const float* __restrict__ vals, const int* __restrict__ rows,
                               const int* __restrict__ cols, int nnz) {
    int tid = blockIdx.x * blockDim.x + threadIdx.x;
    int e = tid >> 4;
    if (e >= nnz) return;
    int c = tid & 15;
    int r = rows[e], col = cols[e];
    float v = vals[e];
    float4 xv = ((const float4*)(x + (size_t)col * EMB))[c];
    float* dst = y + (size_t)r * EMB + (size_t)c * 4;
    atomicAdd(dst + 0, xv.x * v);
    atomicAdd(dst + 1, xv.y * v);
    atomicAdd(dst + 2, xv.z * v);
    atomicAdd(dst + 3, xv.w * v);
}

__global__ void accum_kernel(float* __restrict__ out, const float* __restrict__ y, float scale) {
    int idx = blockIdx.x * blockDim.x + threadIdx.x;
    const int total = NNODE * EMB / 4;
    if (idx >= total) return;
    float4 o = ((float4*)out)[idx];
    float4 a = ((const float4*)y)[idx];
    o.x = (o.x + a.x) * scale; o.y = (o.y + a.y) * scale;
    o.z = (o.z + a.z) * scale; o.w = (o.w + a.w) * scale;
    ((float4*)out)[idx] = o;
}

extern "C" void kernel_launch(void* const* d_in, const int* in_sizes, int n_in,
                              void* d_out, int out_size, void* d_ws, size_t ws_size,
                              hipStream_t stream) {
    const float* user_emb = (const float*)d_in[0];
    const float* item_emb = (const float*)d_in[1];
    const float* vals     = (const float*)d_in[2];
    const int*   rows     = (const int*)d_in[3];
    const int*   cols     = (const int*)d_in[4];
    const int    nnz      = in_sizes[2];

    float* out = (float*)d_out;

    const size_t embN = (size_t)NNODE * EMB;          // 7,680,000 floats
    const size_t rp_pad = 120064;                     // NNODE+1 rounded up

    // ws layout (floats/ints):
    //   bufA: embN floats        (cursor aliases front of bufA during build)
    //   bufB: embN floats        (counts aliases front of bufB during build)
    //   row_ptr: rp_pad ints
    //   cols_s:  nnz ints
    //   vals_s:  nnz floats
    //   bsums:   512 ints
    size_t need = (2 * embN + rp_pad + 2 * (size_t)nnz + 512) * 4;

    if (ws_size >= need) {
        float* bufA    = (float*)d_ws;
        float* bufB    = bufA + embN;
        int*   row_ptr = (int*)(bufB + embN);
        int*   cols_s  = row_ptr + rp_pad;
        float* vals_s  = (float*)(cols_s + nnz);
        int*   bsums   = (int*)(vals_s + nnz);
        int*   cursor  = (int*)bufA;   // alias: build finishes before layer1 writes bufA
        int*   counts  = (int*)bufB;   // alias: build finishes before layer2 writes bufB

        const int nb = (NNODE + SCAN_BS - 1) / SCAN_BS;   // 469 <= 512

        // --- build CSR ---
        hipMemsetAsync(counts, 0, (size_t)NNODE * sizeof(int), stream);
        hist_kernel<<<(nnz + 255) / 256, 256, 0, stream>>>(rows, counts, nnz);
        block_sum_kernel<<<nb, SCAN_BS, 0, stream>>>(counts, bsums, NNODE);
        scan_bsums_kernel<<<1, 512, 0, stream>>>(bsums, nb);
        write_rowptr_kernel<<<nb, SCAN_BS, 0, stream>>>(counts, bsums, row_ptr, cursor, NNODE, nnz);
        fill_kernel<<<(nnz + 255) / 256, 256, 0, stream>>>(rows, cols, vals, cursor, cols_s, vals_s, nnz);

        // --- 3 propagation layers, accumulation fused into epilogues ---
        const int blocks = (NNODE + 3) / 4;   // 4 waves (rows) per 256-thread block
        spmm_kernel<1><<<blocks, 256, 0, stream>>>(user_emb, item_emb, row_ptr, cols_s, vals_s, bufA, out);
        spmm_kernel<2><<<blocks, 256, 0, stream>>>(bufA, nullptr, row_ptr, cols_s, vals_s, bufB, out);
        spmm_kernel<3><<<blocks, 256, 0, stream>>>(bufB, nullptr, row_ptr, cols_s, vals_s, nullptr, out);
    } else {
        // fallback: atomic scatter path (round 1)
        float* x = (float*)d_ws;
        float* y = x + embN;
        const size_t emb_bytes = embN * sizeof(float);
        {
            int total = NNODE * EMB / 4;
            init_kernel<<<(total + 255) / 256, 256, 0, stream>>>(user_emb, item_emb, x, out);
        }
        for (int layer = 0; layer < 3; ++layer) {
            hipMemsetAsync(y, 0, emb_bytes, stream);
            long long threads = (long long)nnz * 16;
            scatter_kernel<<<(int)((threads + 255) / 256), 256, 0, stream>>>(x, y, vals, rows, cols, nnz);
            int total = NNODE * EMB / 4;
            accum_kernel<<<(total + 255) / 256, 256, 0, stream>>>(out, y, layer < 2 ? 1.0f : (1.0f / 3.0f));
            float* t = x; x = y; y = t;
        }
    }
}

// Round 3
// 382.666 us; speedup vs baseline: 8.3283x; 1.5116x over previous
//
#include <hip/hip_runtime.h>

#define USER_NUM 80000
#define ITEM_NUM 40000
#define NNODE (USER_NUM + ITEM_NUM)
#define EMB 64
#define SCAN_BS 256

// ===========================================================================
// CSR build
// ===========================================================================
__global__ void hist_kernel(const int* __restrict__ rows, int* __restrict__ counts, int nnz) {
    int i = blockIdx.x * blockDim.x + threadIdx.x;
    if (i < nnz) atomicAdd(&counts[rows[i]], 1);
}

__global__ void block_sum_kernel(const int* __restrict__ counts, int* __restrict__ bsums, int n) {
    __shared__ int lds[SCAN_BS];
    int t = threadIdx.x;
    int i = blockIdx.x * SCAN_BS + t;
    lds[t] = (i < n) ? counts[i] : 0;
    __syncthreads();
    for (int off = SCAN_BS / 2; off > 0; off >>= 1) {
        if (t < off) lds[t] += lds[t + off];
        __syncthreads();
    }
    if (t == 0) bsums[blockIdx.x] = lds[0];
}

// single block of 512 threads, exclusive scan of nb (<=512) block sums in place
__global__ void scan_bsums_kernel(int* bsums, int nb) {
    __shared__ int lds[512];
    int t = threadIdx.x;
    int v = (t < nb) ? bsums[t] : 0;
    lds[t] = v;
    __syncthreads();
    for (int off = 1; off < 512; off <<= 1) {
        int add = (t >= off) ? lds[t - off] : 0;
        __syncthreads();
        lds[t] += add;
        __syncthreads();
    }
    if (t < nb) bsums[t] = lds[t] - v;  // exclusive
}

__global__ void write_rowptr_kernel(const int* __restrict__ counts, const int* __restrict__ bsums,
                                    int* __restrict__ row_ptr, int* __restrict__ cursor,
                                    int n, int nnz) {
    __shared__ int lds[SCAN_BS];
    int t = threadIdx.x;
    int i = blockIdx.x * SCAN_BS + t;
    int v = (i < n) ? counts[i] : 0;
    lds[t] = v;
    __syncthreads();
    for (int off = 1; off < SCAN_BS; off <<= 1) {
        int add = (t >= off) ? lds[t - off] : 0;
        __syncthreads();
        lds[t] += add;
        __syncthreads();
    }
    if (i < n) {
        int ex = lds[t] - v + bsums[blockIdx.x];
        row_ptr[i] = ex;
        cursor[i]  = ex;
    }
    if (i == 0) row_ptr[n] = nnz;
}

__global__ void fill_kernel(const int* __restrict__ rows, const int* __restrict__ cols,
                            const float* __restrict__ vals, int* __restrict__ cursor,
                            int2* __restrict__ edges, int nnz) {
    int i = blockIdx.x * blockDim.x + threadIdx.x;
    if (i >= nnz) return;
    int r = rows[i];
    int pos = atomicAdd(&cursor[r], 1);
    edges[pos] = make_int2(cols[i], __float_as_int(vals[i]));
}

// ===========================================================================
// CSR SpMM: one wave per row, lane = emb dim.
//  - lane l bulk-loads edges[start+l] (coalesced int2)
//  - per-edge (col,val) broadcast via v_readlane (SGPR, no mem dependency)
//  - unroll 4 with 4 accumulators; count padded to x4 with zero-val edges
// Epilogue fuses layer accumulation: L1: out=y1; L2: out+=y2; L3: out=(out+y3)/3.
// ===========================================================================
template <int LAYER>
__launch_bounds__(256)
__global__ void spmm_kernel(const float* __restrict__ xu, const float* __restrict__ xi,
                            const int* __restrict__ row_ptr, const int2* __restrict__ edges,
                            float* __restrict__ y, float* __restrict__ out) {
    int row  = (blockIdx.x * blockDim.x + threadIdx.x) >> 6;
    int lane = threadIdx.x & 63;
    if (row >= NNODE) return;
    int start = row_ptr[row];
    int end   = row_ptr[row + 1];

    float a0 = 0.f, a1 = 0.f, a2 = 0.f, a3 = 0.f;

    for (int base = start; base < end; base += 64) {
        int idx = base + lane;
        int2 e  = (idx < end) ? edges[idx] : make_int2(0, 0);  // val bits 0 -> 0.0f
        int cnt = end - base; if (cnt > 64) cnt = 64;
        int cnt_pad = (cnt + 3) & ~3;
        #pragma nounroll
        for (int j = 0; j < cnt_pad; j += 4) {
            int c0 = __builtin_amdgcn_readlane(e.x, j);
            int c1 = __builtin_amdgcn_readlane(e.x, j + 1);
            int c2 = __builtin_amdgcn_readlane(e.x, j + 2);
            int c3 = __builtin_amdgcn_readlane(e.x, j + 3);
            float v0 = __int_as_float(__builtin_amdgcn_readlane(e.y, j));
            float v1 = __int_as_float(__builtin_amdgcn_readlane(e.y, j + 1));
            float v2 = __int_as_float(__builtin_amdgcn_readlane(e.y, j + 2));
            float v3 = __int_as_float(__builtin_amdgcn_readlane(e.y, j + 3));
            const float *p0, *p1, *p2, *p3;
            if (LAYER == 1) {
                p0 = (c0 < USER_NUM) ? xu + (size_t)c0 * EMB : xi + (size_t)(c0 - USER_NUM) * EMB;
                p1 = (c1 < USER_NUM) ? xu + (size_t)c1 * EMB : xi + (size_t)(c1 - USER_NUM) * EMB;
                p2 = (c2 < USER_NUM) ? xu + (size_t)c2 * EMB : xi + (size_t)(c2 - USER_NUM) * EMB;
                p3 = (c3 < USER_NUM) ? xu + (size_t)c3 * EMB : xi + (size_t)(c3 - USER_NUM) * EMB;
            } else {
                p0 = xu + (size_t)c0 * EMB;
                p1 = xu + (size_t)c1 * EMB;
                p2 = xu + (size_t)c2 * EMB;
                p3 = xu + (size_t)c3 * EMB;
            }
            float g0 = p0[lane], g1 = p1[lane], g2 = p2[lane], g3 = p3[lane];
            a0 += v0 * g0;
            a1 += v1 * g1;
            a2 += v2 * g2;
            a3 += v3 * g3;
        }
    }

    float acc = (a0 + a1) + (a2 + a3);
    size_t o = (size_t)row * EMB + lane;
    if (LAYER == 1) {
        y[o] = acc;
        out[o] = acc;
    } else if (LAYER == 2) {
        y[o] = acc;
        out[o] += acc;
    } else {
        out[o] = (out[o] + acc) * (1.0f / 3.0f);
    }
}

// ===========================================================================
// Fallback (atomic path) in case ws_size is too small for CSR arrays
// ===========================================================================
__global__ void init_kernel(const float* __restrict__ user_emb, const float* __restrict__ item_emb,
                            float* __restrict__ x, float* __restrict__ out) {
    int idx = blockIdx.x * blockDim.x + threadIdx.x;
    const int total = NNODE * EMB / 4;
    if (idx >= total) return;
    const int user_total = USER_NUM * EMB / 4;
    float4 v = (idx < user_total) ? ((const float4*)user_emb)[idx]
                                  : ((const float4*)item_emb)[idx - user_total];
    ((float4*)x)[idx]   = v;
    ((float4*)out)[idx] = make_float4(0.f, 0.f, 0.f, 0.f);
}

__global__ void scatter_kernel(const float* __restrict__ x, float* __restrict__ y,
                               const float* __restrict__ vals, const int* __restrict__ rows,
                               const int* __restrict__ cols, int nnz) {
    int tid = blockIdx.x * blockDim.x + threadIdx.x;
    int e = tid >> 4;
    if (e >= nnz) return;
    int c = tid & 15;
    int r = rows[e], col = cols[e];
    float v = vals[e];
    float4 xv = ((const float4*)(x + (size_t)col * EMB))[c];
    float* dst = y + (size_t)r * EMB + (size_t)c * 4;
    atomicAdd(dst + 0, xv.x * v);
    atomicAdd(dst + 1, xv.y * v);
    atomicAdd(dst + 2, xv.z * v);
    atomicAdd(dst + 3, xv.w * v);
}

__global__ void accum_kernel(float* __restrict__ out, const float* __restrict__ y, float scale) {
    int idx = blockIdx.x * blockDim.x + threadIdx.x;
    const int total = NNODE * EMB / 4;
    if (idx >= total) return;
    float4 o = ((float4*)out)[idx];
    float4 a = ((const float4*)y)[idx];
    o.x = (o.x + a.x) * scale; o.y = (o.y + a.y) * scale;
    o.z = (o.z + a.z) * scale; o.w = (o.w + a.w) * scale;
    ((float4*)out)[idx] = o;
}

extern "C" void kernel_launch(void* const* d_in, const int* in_sizes, int n_in,
                              void* d_out, int out_size, void* d_ws, size_t ws_size,
                              hipStream_t stream) {
    const float* user_emb = (const float*)d_in[0];
    const float* item_emb = (const float*)d_in[1];
    const float* vals     = (const float*)d_in[2];
    const int*   rows     = (const int*)d_in[3];
    const int*   cols     = (const int*)d_in[4];
    const int    nnz      = in_sizes[2];

    float* out = (float*)d_out;

    const size_t embN   = (size_t)NNODE * EMB;        // 7,680,000 floats
    const size_t rp_pad = 120064;                     // NNODE+1 rounded up (8B-align after)

    // ws layout:
    //   bufA: embN floats        (cursor aliases front of bufA during build)
    //   bufB: embN floats        (counts aliases front of bufB during build)
    //   row_ptr: rp_pad ints
    //   edges:   nnz int2        (packed {col, val})
    //   bsums:   512 ints
    size_t need = (2 * embN + rp_pad + 512) * 4 + (size_t)nnz * 8;

    if (ws_size >= need) {
        float* bufA    = (float*)d_ws;
        float* bufB    = bufA + embN;
        int*   row_ptr = (int*)(bufB + embN);
        int2*  edges   = (int2*)(row_ptr + rp_pad);
        int*   bsums   = (int*)(edges + nnz);
        int*   cursor  = (int*)bufA;   // alias: build finishes before layer1 writes bufA
        int*   counts  = (int*)bufB;   // alias: build finishes before layer2 writes bufB

        const int nb = (NNODE + SCAN_BS - 1) / SCAN_BS;   // 469 <= 512

        // --- build CSR ---
        hipMemsetAsync(counts, 0, (size_t)NNODE * sizeof(int), stream);
        hist_kernel<<<(nnz + 255) / 256, 256, 0, stream>>>(rows, counts, nnz);
        block_sum_kernel<<<nb, SCAN_BS, 0, stream>>>(counts, bsums, NNODE);
        scan_bsums_kernel<<<1, 512, 0, stream>>>(bsums, nb);
        write_rowptr_kernel<<<nb, SCAN_BS, 0, stream>>>(counts, bsums, row_ptr, cursor, NNODE, nnz);
        fill_kernel<<<(nnz + 255) / 256, 256, 0, stream>>>(rows, cols, vals, cursor, edges, nnz);

        // --- 3 propagation layers, accumulation fused into epilogues ---
        const int blocks = (NNODE + 3) / 4;   // 4 waves (rows) per 256-thread block
        spmm_kernel<1><<<blocks, 256, 0, stream>>>(user_emb, item_emb, row_ptr, edges, bufA, out);
        spmm_kernel<2><<<blocks, 256, 0, stream>>>(bufA, nullptr, row_ptr, edges, bufB, out);
        spmm_kernel<3><<<blocks, 256, 0, stream>>>(bufB, nullptr, row_ptr, edges, nullptr, out);
    } else {
        // fallback: atomic scatter path
        float* x = (float*)d_ws;
        float* y = x + embN;
        const size_t emb_bytes = embN * sizeof(float);
        {
            int total = NNODE * EMB / 4;
            init_kernel<<<(total + 255) / 256, 256, 0, stream>>>(user_emb, item_emb, x, out);
        }
        for (int layer = 0; layer < 3; ++layer) {
            hipMemsetAsync(y, 0, emb_bytes, stream);
            long long threads = (long long)nnz * 16;
            scatter_kernel<<<(int)((threads + 255) / 256), 256, 0, stream>>>(x, y, vals, rows, cols, nnz);
            int total = NNODE * EMB / 4;
            accum_kernel<<<(total + 255) / 256, 256, 0, stream>>>(out, y, layer < 2 ? 1.0f : (1.0f / 3.0f));
            float* t = x; x = y; y = t;
        }
    }
}

// Round 4
// 299.250 us; speedup vs baseline: 10.6498x; 1.2788x over previous
//
#include <hip/hip_runtime.h>

#define USER_NUM 80000
#define ITEM_NUM 40000
#define NNODE (USER_NUM + ITEM_NUM)
#define EMB 64
#define NB 469            // ceil(NNODE / 256) buckets of 256 rows
#define P1_CHUNK 4096

// ===========================================================================
// Build step 1: coarse histogram of row>>8 (LDS-aggregated)
// ===========================================================================
__global__ void bucket_hist_kernel(const int* __restrict__ rows, int* __restrict__ bcounts, int nnz) {
    __shared__ int h[NB];
    for (int i = threadIdx.x; i < NB; i += blockDim.x) h[i] = 0;
    __syncthreads();
    int stride = gridDim.x * blockDim.x;
    for (int i = blockIdx.x * blockDim.x + threadIdx.x; i < nnz; i += stride)
        atomicAdd(&h[rows[i] >> 8], 1);
    __syncthreads();
    for (int i = threadIdx.x; i < NB; i += blockDim.x)
        if (h[i]) atomicAdd(&bcounts[i], h[i]);
}

// ===========================================================================
// Build step 2: exclusive scan of 469 bucket counts (single block)
// ===========================================================================
__global__ void bucket_scan_kernel(const int* __restrict__ bcounts, int* __restrict__ bucket_off,
                                   int* __restrict__ bcursor, int* __restrict__ row_ptr, int nnz) {
    __shared__ int lds[512];
    int t = threadIdx.x;
    int v = (t < NB) ? bcounts[t] : 0;
    lds[t] = v;
    __syncthreads();
    for (int off = 1; off < 512; off <<= 1) {
        int add = (t >= off) ? lds[t - off] : 0;
        __syncthreads();
        lds[t] += add;
        __syncthreads();
    }
    if (t < NB) {
        int ex = lds[t] - v;
        bucket_off[t] = ex;
        bcursor[t]    = ex;
    }
    if (t == 0) { bucket_off[NB] = nnz; row_ptr[NNODE] = nnz; }
}

// ===========================================================================
// Build step 3: bin edges into buckets. Per-block LDS histogram -> one global
// atomic per (block,bucket) -> sequential writes per bucket (line-friendly).
// tmp entry packs {col | row_local<<17, val_bits}.
// ===========================================================================
__global__ void phase1_kernel(const int* __restrict__ rows, const int* __restrict__ cols,
                              const float* __restrict__ vals, int* __restrict__ bcursor,
                              int2* __restrict__ tmp, int nnz) {
    __shared__ int h[NB];
    __shared__ int base[NB];
    int t = threadIdx.x;
    for (int i = t; i < NB; i += 256) h[i] = 0;
    __syncthreads();
    int lo = blockIdx.x * P1_CHUNK;
    int hi = lo + P1_CHUNK; if (hi > nnz) hi = nnz;
    for (int i = lo + t; i < hi; i += 256)
        atomicAdd(&h[rows[i] >> 8], 1);
    __syncthreads();
    for (int i = t; i < NB; i += 256) {
        int c = h[i];
        base[i] = c ? atomicAdd(&bcursor[i], c) : 0;
        h[i] = 0;
    }
    __syncthreads();
    for (int i = lo + t; i < hi; i += 256) {
        int r = rows[i];
        int b = r >> 8;
        int loc = atomicAdd(&h[b], 1);
        tmp[base[b] + loc] = make_int2(cols[i] | ((r & 255) << 17), __float_as_int(vals[i]));
    }
}

// ===========================================================================
// Build step 4: one block per bucket. Exact per-row counts + scan give
// row_ptr for the bucket's 256 rows; LDS cursors place edges into final CSR.
// All scatter randomness confined to the bucket's ~20 KB window (L2-hot).
// ===========================================================================
__global__ void phase2_kernel(const int2* __restrict__ tmp, const int* __restrict__ bucket_off,
                              int* __restrict__ row_ptr, int2* __restrict__ edges) {
    __shared__ int hist[256];
    __shared__ int scan[256];
    __shared__ int cur[256];
    int b = blockIdx.x;
    int t = threadIdx.x;
    int row0  = b << 8;
    int nrows = NNODE - row0; if (nrows > 256) nrows = 256;
    int start = bucket_off[b];
    int end   = bucket_off[b + 1];
    hist[t] = 0;
    __syncthreads();
    for (int j = start + t; j < end; j += 256)
        atomicAdd(&hist[tmp[j].x >> 17], 1);
    __syncthreads();
    int v = hist[t];
    scan[t] = v;
    __syncthreads();
    for (int off = 1; off < 256; off <<= 1) {
        int add = (t >= off) ? scan[t - off] : 0;
        __syncthreads();
        scan[t] += add;
        __syncthreads();
    }
    int ex = scan[t] - v + start;   // exclusive prefix + bucket base
    if (t < nrows) row_ptr[row0 + t] = ex;
    cur[t] = ex;
    __syncthreads();
    for (int j = start + t; j < end; j += 256) {
        int2 e  = tmp[j];
        int rl  = e.x >> 17;
        int pos = atomicAdd(&cur[rl], 1);
        edges[pos] = make_int2(e.x & 0x1FFFF, e.y);
    }
}

// ===========================================================================
// CSR SpMM: one wave per row, lane = emb dim (unchanged from R3).
// ===========================================================================
template <int LAYER>
__launch_bounds__(256)
__global__ void spmm_kernel(const float* __restrict__ xu, const float* __restrict__ xi,
                            const int* __restrict__ row_ptr, const int2* __restrict__ edges,
                            float* __restrict__ y, float* __restrict__ out) {
    int row  = (blockIdx.x * blockDim.x + threadIdx.x) >> 6;
    int lane = threadIdx.x & 63;
    if (row >= NNODE) return;
    int start = row_ptr[row];
    int end   = row_ptr[row + 1];

    float a0 = 0.f, a1 = 0.f, a2 = 0.f, a3 = 0.f;

    for (int base = start; base < end; base += 64) {
        int idx = base + lane;
        int2 e  = (idx < end) ? edges[idx] : make_int2(0, 0);  // val bits 0 -> 0.0f
        int cnt = end - base; if (cnt > 64) cnt = 64;
        int cnt_pad = (cnt + 3) & ~3;
        #pragma nounroll
        for (int j = 0; j < cnt_pad; j += 4) {
            int c0 = __builtin_amdgcn_readlane(e.x, j);
            int c1 = __builtin_amdgcn_readlane(e.x, j + 1);
            int c2 = __builtin_amdgcn_readlane(e.x, j + 2);
            int c3 = __builtin_amdgcn_readlane(e.x, j + 3);
            float v0 = __int_as_float(__builtin_amdgcn_readlane(e.y, j));
            float v1 = __int_as_float(__builtin_amdgcn_readlane(e.y, j + 1));
            float v2 = __int_as_float(__builtin_amdgcn_readlane(e.y, j + 2));
            float v3 = __int_as_float(__builtin_amdgcn_readlane(e.y, j + 3));
            const float *p0, *p1, *p2, *p3;
            if (LAYER == 1) {
                p0 = (c0 < USER_NUM) ? xu + (size_t)c0 * EMB : xi + (size_t)(c0 - USER_NUM) * EMB;
                p1 = (c1 < USER_NUM) ? xu + (size_t)c1 * EMB : xi + (size_t)(c1 - USER_NUM) * EMB;
                p2 = (c2 < USER_NUM) ? xu + (size_t)c2 * EMB : xi + (size_t)(c2 - USER_NUM) * EMB;
                p3 = (c3 < USER_NUM) ? xu + (size_t)c3 * EMB : xi + (size_t)(c3 - USER_NUM) * EMB;
            } else {
                p0 = xu + (size_t)c0 * EMB;
                p1 = xu + (size_t)c1 * EMB;
                p2 = xu + (size_t)c2 * EMB;
                p3 = xu + (size_t)c3 * EMB;
            }
            float g0 = p0[lane], g1 = p1[lane], g2 = p2[lane], g3 = p3[lane];
            a0 += v0 * g0;
            a1 += v1 * g1;
            a2 += v2 * g2;
            a3 += v3 * g3;
        }
    }

    float acc = (a0 + a1) + (a2 + a3);
    size_t o = (size_t)row * EMB + lane;
    if (LAYER == 1) {
        y[o] = acc;
        out[o] = acc;
    } else if (LAYER == 2) {
        y[o] = acc;
        out[o] += acc;
    } else {
        out[o] = (out[o] + acc) * (1.0f / 3.0f);
    }
}

// ===========================================================================
// Fallback (atomic path) in case ws_size is too small for CSR arrays
// ===========================================================================
__global__ void init_kernel(const float* __restrict__ user_emb, const float* __restrict__ item_emb,
                            float* __restrict__ x, float* __restrict__ out) {
    int idx = blockIdx.x * blockDim.x + threadIdx.x;
    const int total = NNODE * EMB / 4;
    if (idx >= total) return;
    const int user_total = USER_NUM * EMB / 4;
    float4 v = (idx < user_total) ? ((const float4*)user_emb)[idx]
                                  : ((const float4*)item_emb)[idx - user_total];
    ((float4*)x)[idx]   = v;
    ((float4*)out)[idx] = make_float4(0.f, 0.f, 0.f, 0.f);
}

__global__ void scatter_kernel(const float* __restrict__ x, float* __restrict__ y,
                               const float* __restrict__ vals, const int* __restrict__ rows,
                               const int* __restrict__ cols, int nnz) {
    int tid = blockIdx.x * blockDim.x + threadIdx.x;
    int e = tid >> 4;
    if (e >= nnz) return;
    int c = tid & 15;
    int r = rows[e], col = cols[e];
    float v = vals[e];
    float4 xv = ((const float4*)(x + (size_t)col * EMB))[c];
    float* dst = y + (size_t)r * EMB + (size_t)c * 4;
    atomicAdd(dst + 0, xv.x * v);
    atomicAdd(dst + 1, xv.y * v);
    atomicAdd(dst + 2, xv.z * v);
    atomicAdd(dst + 3, xv.w * v);
}

__global__ void accum_kernel(float* __restrict__ out, const float* __restrict__ y, float scale) {
    int idx = blockIdx.x * blockDim.x + threadIdx.x;
    const int total = NNODE * EMB / 4;
    if (idx >= total) return;
    float4 o = ((float4*)out)[idx];
    float4 a = ((const float4*)y)[idx];
    o.x = (o.x + a.x) * scale; o.y = (o.y + a.y) * scale;
    o.z = (o.z + a.z) * scale; o.w = (o.w + a.w) * scale;
    ((float4*)out)[idx] = o;
}

extern "C" void kernel_launch(void* const* d_in, const int* in_sizes, int n_in,
                              void* d_out, int out_size, void* d_ws, size_t ws_size,
                              hipStream_t stream) {
    const float* user_emb = (const float*)d_in[0];
    const float* item_emb = (const float*)d_in[1];
    const float* vals     = (const float*)d_in[2];
    const int*   rows     = (const int*)d_in[3];
    const int*   cols     = (const int*)d_in[4];
    const int    nnz      = in_sizes[2];

    float* out = (float*)d_out;

    const size_t embN   = (size_t)NNODE * EMB;        // 7,680,000 floats
    const size_t rp_pad = 120064;                     // NNODE+1 rounded up (8B-align after)

    // Persistent ws layout (survives through spmm layers):
    //   bufA: embN floats   | bufB: embN floats | row_ptr: rp_pad ints | edges: nnz int2
    // Build-time aliases (dead before their host buffer is written):
    //   tmp (nnz int2)         -> front of bufA   (bufA written by spmm<1>)
    //   bcounts/bucket_off/bcursor (3*512 ints) -> front of bufB (bufB written by spmm<2>)
    size_t need = (2 * embN + rp_pad) * 4 + (size_t)nnz * 8;

    if (ws_size >= need) {
        float* bufA    = (float*)d_ws;
        float* bufB    = bufA + embN;
        int*   row_ptr = (int*)(bufB + embN);
        int2*  edges   = (int2*)(row_ptr + rp_pad);

        int2* tmp        = (int2*)bufA;
        int*  bcounts    = (int*)bufB;
        int*  bucket_off = bcounts + 512;       // NB+1 used
        int*  bcursor    = bucket_off + 512;

        // --- build CSR (two-pass LDS-binned counting sort) ---
        hipMemsetAsync(bcounts, 0, NB * sizeof(int), stream);
        bucket_hist_kernel<<<256, 256, 0, stream>>>(rows, bcounts, nnz);
        bucket_scan_kernel<<<1, 512, 0, stream>>>(bcounts, bucket_off, bcursor, row_ptr, nnz);
        phase1_kernel<<<(nnz + P1_CHUNK - 1) / P1_CHUNK, 256, 0, stream>>>(rows, cols, vals, bcursor, tmp, nnz);
        phase2_kernel<<<NB, 256, 0, stream>>>(tmp, bucket_off, row_ptr, edges);

        // --- 3 propagation layers, accumulation fused into epilogues ---
        const int blocks = (NNODE + 3) / 4;   // 4 waves (rows) per 256-thread block
        spmm_kernel<1><<<blocks, 256, 0, stream>>>(user_emb, item_emb, row_ptr, edges, bufA, out);
        spmm_kernel<2><<<blocks, 256, 0, stream>>>(bufA, nullptr, row_ptr, edges, bufB, out);
        spmm_kernel<3><<<blocks, 256, 0, stream>>>(bufB, nullptr, row_ptr, edges, nullptr, out);
    } else {
        // fallback: atomic scatter path
        float* x = (float*)d_ws;
        float* y = x + embN;
        const size_t emb_bytes = embN * sizeof(float);
        {
            int total = NNODE * EMB / 4;
            init_kernel<<<(total + 255) / 256, 256, 0, stream>>>(user_emb, item_emb, x, out);
        }
        for (int layer = 0; layer < 3; ++layer) {
            hipMemsetAsync(y, 0, emb_bytes, stream);
            long long threads = (long long)nnz * 16;
            scatter_kernel<<<(int)((threads + 255) / 256), 256, 0, stream>>>(x, y, vals, rows, cols, nnz);
            int total = NNODE * EMB / 4;
            accum_kernel<<<(total + 255) / 256, 256, 0, stream>>>(out, y, layer < 2 ? 1.0f : (1.0f / 3.0f));
            float* t = x; x = y; y = t;
        }
    }
}